// Round 1
// baseline (16748.799 us; speedup 1.0000x reference)
//
#include <hip/hip_runtime.h>

#define H 1024
#define EM 512
#define TSTEPS 2048
#define OSZ 32000
#define FOURH 4096
#define NWG 128

typedef __attribute__((ext_vector_type(8))) short short8;
typedef __attribute__((ext_vector_type(4))) float f32x4;

__device__ __forceinline__ unsigned short f2bf(float f) {
  union { float f; unsigned int u; } x; x.f = f;
  unsigned int r = x.u + 0x7FFFu + ((x.u >> 16) & 1u);   // RNE
  return (unsigned short)(r >> 16);
}
__device__ __forceinline__ unsigned int pk2(float lo, float hi) {
  return (unsigned int)f2bf(lo) | ((unsigned int)f2bf(hi) << 16);
}
__device__ __forceinline__ float sigm(float x) { return 1.0f / (1.0f + expf(-x)); }

// ---------------- embedding gathers ----------------
__global__ void gather_k(const int* __restrict__ e1, const int* __restrict__ gt,
                         const float* __restrict__ emb_i, const float* __restrict__ emb_o,
                         float* __restrict__ enc_e, float* __restrict__ dec_e) {
  int row = blockIdx.x;
  int t4 = threadIdx.x * 4;
  if (blockIdx.y == 0) {
    int idx = e1[row];
    *(float4*)&enc_e[(size_t)row * EM + t4] = *(const float4*)&emb_i[(size_t)idx * EM + t4];
  } else {
    int idx = (row == 0) ? 1 : gt[row - 1];
    *(float4*)&dec_e[(size_t)row * EM + t4] = *(const float4*)&emb_o[(size_t)idx * EM + t4];
  }
}

// ------------- C[M,N] = A[M,K] @ B[N,K]^T + bias1 + bias2 (bf16 MFMA) -------------
#define LDT 40
__global__ __launch_bounds__(256) void gemm_bt(
    const float* __restrict__ A, const float* __restrict__ B,
    const float* __restrict__ bias1, const float* __restrict__ bias2,
    float* __restrict__ C, int M, int N, int K) {
  __shared__ __align__(16) unsigned short aL[64 * LDT];
  __shared__ __align__(16) unsigned short bL[64 * LDT];
  int tid = threadIdx.x;
  int n0 = blockIdx.x * 64, m0 = blockIdx.y * 64;
  int wv = tid >> 6, l = tid & 63;
  int wm = (wv >> 1) * 32, wn = (wv & 1) * 32;
  int col = l & 15, quad = l >> 4;
  f32x4 acc[2][2];
  acc[0][0] = (f32x4){0,0,0,0}; acc[0][1] = (f32x4){0,0,0,0};
  acc[1][0] = (f32x4){0,0,0,0}; acc[1][1] = (f32x4){0,0,0,0};

  int r = tid >> 2, c8 = (tid & 3) * 8;
  const float* ap = A + (size_t)(m0 + r) * K + c8;
  const float* bp = B + (size_t)(n0 + r) * K + c8;

  for (int k0 = 0; k0 < K; k0 += 32) {
    float4 a0 = *(const float4*)(ap + k0);
    float4 a1 = *(const float4*)(ap + k0 + 4);
    float4 b0 = *(const float4*)(bp + k0);
    float4 b1 = *(const float4*)(bp + k0 + 4);
    uint4 apk, bpk;
    apk.x = pk2(a0.x, a0.y); apk.y = pk2(a0.z, a0.w);
    apk.z = pk2(a1.x, a1.y); apk.w = pk2(a1.z, a1.w);
    bpk.x = pk2(b0.x, b0.y); bpk.y = pk2(b0.z, b0.w);
    bpk.z = pk2(b1.x, b1.y); bpk.w = pk2(b1.z, b1.w);
    *(uint4*)&aL[r * LDT + c8] = apk;
    *(uint4*)&bL[r * LDT + c8] = bpk;
    __syncthreads();

    short8 af0 = *(const short8*)&aL[(wm + col) * LDT + quad * 8];
    short8 af1 = *(const short8*)&aL[(wm + 16 + col) * LDT + quad * 8];
    short8 bf0 = *(const short8*)&bL[(wn + col) * LDT + quad * 8];
    short8 bf1 = *(const short8*)&bL[(wn + 16 + col) * LDT + quad * 8];
    acc[0][0] = __builtin_amdgcn_mfma_f32_16x16x32_bf16(af0, bf0, acc[0][0], 0, 0, 0);
    acc[0][1] = __builtin_amdgcn_mfma_f32_16x16x32_bf16(af0, bf1, acc[0][1], 0, 0, 0);
    acc[1][0] = __builtin_amdgcn_mfma_f32_16x16x32_bf16(af1, bf0, acc[1][0], 0, 0, 0);
    acc[1][1] = __builtin_amdgcn_mfma_f32_16x16x32_bf16(af1, bf1, acc[1][1], 0, 0, 0);
    __syncthreads();
  }

  #pragma unroll
  for (int j = 0; j < 2; ++j) {
    int n = n0 + wn + j * 16 + col;
    float b = (bias1 ? bias1[n] : 0.0f) + (bias2 ? bias2[n] : 0.0f);
    #pragma unroll
    for (int i = 0; i < 2; ++i) {
      #pragma unroll
      for (int rg = 0; rg < 4; ++rg) {
        int m = m0 + wm + i * 16 + quad * 4 + rg;
        C[(size_t)m * N + n] = acc[i][j][rg] + b;
      }
    }
  }
}

// ---------------- persistent LSTM recurrence ----------------
// 128 WGs x 256 thr. WG wg owns h indices [wg*8, wg*8+8). Wave w = gate w (i,f,g,o).
// Lane l: a=l>>4 handles gate rows {a, a+4}; q=l&15 handles cols [q*64, q*64+64).
// Whh slice register-resident (128 fp32/lane). c in LDS. h exchanged via
// (fp32 value, canary=t+1) 8B agent-scope atomic pairs; data IS the flag.
__global__ __launch_bounds__(256, 1) void lstm_k(
    const float* __restrict__ xg, const float* __restrict__ Whh,
    const float* __restrict__ h0c0, unsigned long long* __restrict__ pair,
    float* __restrict__ hs, float* __restrict__ c_out) {
  __shared__ float h_lds[H];
  __shared__ float gate_lds[32];
  __shared__ float c_lds[8];
  int tid = threadIdx.x;
  int wg = blockIdx.x;
  int w = tid >> 6, l = tid & 63;
  int a = l >> 4, q = l & 15;
  int hbase = wg * 8;
  int rowA = w * H + hbase + a;
  int rowB = rowA + 4;

  float4 wa[16], wb[16];
  {
    const float4* pa = (const float4*)(Whh + (size_t)rowA * H + q * 64);
    const float4* pb = (const float4*)(Whh + (size_t)rowB * H + q * 64);
    #pragma unroll
    for (int i = 0; i < 16; ++i) { wa[i] = pa[i]; wb[i] = pb[i]; }
  }
  for (int i = tid; i < H; i += 256) h_lds[i] = h0c0 ? h0c0[i] : 0.0f;
  if (tid < 8) c_lds[tid] = h0c0 ? h0c0[hbase + tid] : 0.0f;
  __syncthreads();

  for (int t = 0; t < TSTEPS; ++t) {
    // prefetch this step's xg early (independent of h)
    float xgv = 0.0f;
    if (q < 2) xgv = xg[(size_t)t * FOURH + w * H + hbase + a + (q == 1 ? 4 : 0)];

    // partial matvec over this lane's 64-col chunk
    float sA[4] = {0,0,0,0}, sB[4] = {0,0,0,0};
    #pragma unroll
    for (int i = 0; i < 16; ++i) {
      float4 hv = *(const float4*)&h_lds[q * 64 + i * 4];
      sA[i & 3] += wa[i].x * hv.x + wa[i].y * hv.y + wa[i].z * hv.z + wa[i].w * hv.w;
      sB[i & 3] += wb[i].x * hv.x + wb[i].y * hv.y + wb[i].z * hv.z + wb[i].w * hv.w;
    }
    float accA = (sA[0] + sA[1]) + (sA[2] + sA[3]);
    float accB = (sB[0] + sB[1]) + (sB[2] + sB[3]);
    // reduce across the 16 col-chunks (lane bits 0..3)
    #pragma unroll
    for (int s = 1; s < 16; s <<= 1) {
      accA += __shfl_xor(accA, s);
      accB += __shfl_xor(accB, s);
    }
    if (q == 0)      gate_lds[w * 8 + a]     = accA + xgv;
    else if (q == 1) gate_lds[w * 8 + a + 4] = accB + xgv;
    __syncthreads();

    if (tid < 8) {
      int j = tid;
      float gi = gate_lds[j], gf = gate_lds[8 + j], gg = gate_lds[16 + j], go = gate_lds[24 + j];
      float c = sigm(gf) * c_lds[j] + sigm(gi) * tanhf(gg);
      float h = sigm(go) * tanhf(c);
      c_lds[j] = c;
      unsigned long long pkd = (unsigned long long)__float_as_uint(h) |
                               ((unsigned long long)(unsigned int)(t + 1) << 32);
      __hip_atomic_store(&pair[(size_t)t * H + hbase + j], pkd,
                         __ATOMIC_RELAXED, __HIP_MEMORY_SCOPE_AGENT);
      if (hs) hs[(size_t)t * H + hbase + j] = h;
    }

    if (t + 1 < TSTEPS) {
      int base = tid * 4;
      const unsigned long long* src = pair + (size_t)t * H + base;
      unsigned int want = (unsigned int)(t + 1);
      float v[4]; unsigned int done = 0;
      while (done != 0xFu) {
        #pragma unroll
        for (int i = 0; i < 4; ++i) {
          if (!(done & (1u << i))) {
            unsigned long long p = __hip_atomic_load(&src[i], __ATOMIC_RELAXED,
                                                     __HIP_MEMORY_SCOPE_AGENT);
            if ((unsigned int)(p >> 32) == want) {
              v[i] = __uint_as_float((unsigned int)p);
              done |= (1u << i);
            }
          }
        }
      }
      h_lds[base] = v[0]; h_lds[base + 1] = v[1];
      h_lds[base + 2] = v[2]; h_lds[base + 3] = v[3];
    }
    __syncthreads();
  }
  if (c_out && tid < 8) c_out[hbase + tid] = c_lds[tid];
}

extern "C" void kernel_launch(void* const* d_in, const int* in_sizes, int n_in,
                              void* d_out, int out_size, void* d_ws, size_t ws_size,
                              hipStream_t stream) {
  const int*   e1      = (const int*)d_in[0];
  const int*   gt      = (const int*)d_in[1];
  const float* emb_i   = (const float*)d_in[2];
  const float* emb_o   = (const float*)d_in[3];
  const float* enc_Wih = (const float*)d_in[4];
  const float* enc_Whh = (const float*)d_in[5];
  const float* enc_bih = (const float*)d_in[6];
  const float* enc_bhh = (const float*)d_in[7];
  const float* dec_Wih = (const float*)d_in[8];
  const float* dec_Whh = (const float*)d_in[9];
  const float* dec_bih = (const float*)d_in[10];
  const float* dec_bhh = (const float*)d_in[11];
  const float* outW    = (const float*)d_in[12];
  const float* outb    = (const float*)d_in[13];
  float* out = (float*)d_out;

  char* ws = (char*)d_ws;
  size_t off = 0;
  float* enc_embs = (float*)(ws + off); off += (size_t)TSTEPS * EM * 4;        // 4 MB
  float* dec_embs = (float*)(ws + off); off += (size_t)TSTEPS * EM * 4;        // 4 MB
  float* xg_enc   = (float*)(ws + off); off += (size_t)TSTEPS * FOURH * 4;     // 33.5 MB
  float* xg_dec   = (float*)(ws + off); off += (size_t)TSTEPS * FOURH * 4;     // 33.5 MB
  unsigned long long* pair_enc = (unsigned long long*)(ws + off); off += (size_t)TSTEPS * H * 8;  // 16.8 MB
  unsigned long long* pair_dec = (unsigned long long*)(ws + off); off += (size_t)TSTEPS * H * 8;  // 16.8 MB
  float* enc_c = (float*)(ws + off);    off += (size_t)H * 4;
  float* hs    = (float*)(ws + off);    off += (size_t)TSTEPS * H * 4;         // 8.4 MB

  // 1. embedding gathers
  gather_k<<<dim3(TSTEPS, 2), 128, 0, stream>>>(e1, gt, emb_i, emb_o, enc_embs, dec_embs);
  // 2. encoder x_gates: [2048,512] @ [4096,512]^T + (bih+bhh)
  gemm_bt<<<dim3(FOURH / 64, TSTEPS / 64), 256, 0, stream>>>(
      enc_embs, enc_Wih, enc_bih, enc_bhh, xg_enc, TSTEPS, FOURH, EM);
  // 3. encoder recurrence -> enc_c
  lstm_k<<<NWG, 256, 0, stream>>>(xg_enc, enc_Whh, nullptr, pair_enc, nullptr, enc_c);
  // 4. decoder x_gates
  gemm_bt<<<dim3(FOURH / 64, TSTEPS / 64), 256, 0, stream>>>(
      dec_embs, dec_Wih, dec_bih, dec_bhh, xg_dec, TSTEPS, FOURH, EM);
  // 5. decoder recurrence -> hs
  lstm_k<<<NWG, 256, 0, stream>>>(xg_dec, dec_Whh, enc_c, pair_dec, hs, nullptr);
  // 6. logits: [2048,1024] @ [32000,1024]^T + outb
  gemm_bt<<<dim3(OSZ / 64, TSTEPS / 64), 256, 0, stream>>>(
      hs, outW, outb, nullptr, out, TSTEPS, OSZ, H);
}